// Round 2
// baseline (270.220 us; speedup 1.0000x reference)
//
#include <hip/hip_runtime.h>
#include <stdint.h>

typedef unsigned short u16;
typedef float f32x4 __attribute__((ext_vector_type(4)));
typedef _Float16 half8 __attribute__((ext_vector_type(8)));
typedef __fp16 fp16x2 __attribute__((ext_vector_type(2)));

#define B_  8
#define M_  2
#define DK_ 512
#define D_  256
#define N_  2048
#define DV_ 512

#define OUT_FLOATS (B_*N_*DV_)     /* 8388608 */
#define QB_U16     (B_*M_*N_*D_)   /* 8388608 u16 elements = 16 MiB */

// ---- fp16 pack/unpack helpers -------------------------------------------
__device__ __forceinline__ uint32_t pk16(float a, float b){
    fp16x2 h = __builtin_amdgcn_cvt_pkrtz(a, b);      // v_cvt_pkrtz_f16_f32
    return __builtin_bit_cast(uint32_t, h);
}
__device__ __forceinline__ float h2f_lo(uint32_t u){
    return (float)__builtin_bit_cast(_Float16, (unsigned short)(u & 0xffffu));
}
__device__ __forceinline__ float h2f_hi(uint32_t u){
    return (float)__builtin_bit_cast(_Float16, (unsigned short)(u >> 16));
}

// ============================================================
// K0: transpose-convert qt,kt (fp32 [b, m*256+c, i]) -> f16 [ (b*2+m), row, c ]
// staged into the d_out "output" region (32 MiB, dead until K4 writes O).
// ============================================================
__global__ __launch_bounds__(256) void k0_transpose(const float* __restrict__ qt,
                                                    const float* __restrict__ kt,
                                                    u16* __restrict__ dstBase){
    const int it = blockIdx.x, yc = blockIdx.y, z = blockIdx.z;
    const int b = z & 7, src = z >> 3;
    const float* sp = src ? kt : qt;
    u16* dp = dstBase + (size_t)src * QB_U16;
    const int m = yc >> 2;
    const int cbase = (yc & 3) * 64;
    const int i0 = it * 64;
    __shared__ u16 lds[64 * 72];   // [i][c], pad 72 keeps 16B alignment (144B rows)
    const int t = threadIdx.x;
    {
        const int c_loc = t >> 2;
        const int iq = (t & 3) * 16;
        const float* g = sp + (size_t)(b*DK_ + m*D_ + cbase + c_loc) * N_ + i0 + iq;
        float vv[16];
        *(float4*)&vv[0]  = *(const float4*)(g + 0);
        *(float4*)&vv[4]  = *(const float4*)(g + 4);
        *(float4*)&vv[8]  = *(const float4*)(g + 8);
        *(float4*)&vv[12] = *(const float4*)(g + 12);
        #pragma unroll
        for (int e = 0; e < 16; ++e){
            _Float16 hf = (_Float16)vv[e];
            lds[(iq + e)*72 + c_loc] = __builtin_bit_cast(unsigned short, hf);
        }
    }
    __syncthreads();
    {
        const int i_loc = t >> 2;
        const int cq = (t & 3) * 16;
        uint4 a  = *(const uint4*)&lds[i_loc*72 + cq];
        uint4 b2 = *(const uint4*)&lds[i_loc*72 + cq + 8];
        u16* o = dp + (size_t)((b*M_ + m)*N_ + i0 + i_loc) * D_ + cbase + cq;
        *(uint4*)o = a;
        *(uint4*)(o + 8) = b2;
    }
}

// ============================================================
// K0v (optional, only if ws is big enough): vt fp32 -> f16, same layout.
// ============================================================
__global__ __launch_bounds__(256) void k0_vconv(const float* __restrict__ vt,
                                                u16* __restrict__ vB){
    size_t idx = ((size_t)blockIdx.x * 256 + threadIdx.x) * 8;
    const size_t total = (size_t)B_ * DV_ * N_;
    if (idx < total){
        float4 f0 = *(const float4*)(vt + idx);
        float4 f1 = *(const float4*)(vt + idx + 4);
        uint4 o;
        o.x = pk16(f0.x, f0.y);
        o.y = pk16(f0.z, f0.w);
        o.z = pk16(f1.x, f1.y);
        o.w = pk16(f1.z, f1.w);
        *(uint4*)(vB + idx) = o;
    }
}

// ============================================================
// K1: bar[b][c] = mean_i qt[b][c][i]
// ============================================================
__global__ __launch_bounds__(256) void k1_bar(const float* __restrict__ qt,
                                              float* __restrict__ bar){
    const int cg = blockIdx.x, b = blockIdx.y;
    const int t = threadIdx.x;
    const int c = cg*8 + (t >> 5);
    const int seg = t & 31;
    const float* g = qt + (size_t)(b*DK_ + c)*N_ + seg*64;
    float s = 0.f;
    #pragma unroll
    for (int k = 0; k < 16; ++k){
        float4 f = *(const float4*)(g + k*4);
        s += f.x + f.y + f.z + f.w;
    }
    s += __shfl_xor(s, 1); s += __shfl_xor(s, 2); s += __shfl_xor(s, 4);
    s += __shfl_xor(s, 8); s += __shfl_xor(s, 16);
    if (seg == 0) bar[b*DK_ + c] = s * (1.f / (float)N_);
}

// ============================================================
// K2: logits[b*2+m] = sum_c weight[m,c] * bar[b,c]
// ============================================================
__global__ void k2_logits(const float* __restrict__ wgt,
                          const float* __restrict__ bar,
                          float* __restrict__ wsLog){
    const int bm = blockIdx.x;
    const int b = bm >> 1, m = bm & 1;
    const int l = threadIdx.x; // 64
    float s = 0.f;
    #pragma unroll
    for (int k = 0; k < 8; ++k){
        const int c = l + k*64;
        s += wgt[m*DK_ + c] * bar[b*DK_ + c];
    }
    s += __shfl_xor(s, 1); s += __shfl_xor(s, 2); s += __shfl_xor(s, 4);
    s += __shfl_xor(s, 8); s += __shfl_xor(s, 16); s += __shfl_xor(s, 32);
    if (l == 0) wsLog[bm] = s;
}

// ============================================================
// K3: S = q·k for both mixtures, E = exp(S/sqrt(512)) packed as f16 pair
// (m0 lo, m1 hi) into the dword that will later hold attn[b,i,j] fp32.
// 128x128 tile, BK=64, 4 waves (wave = 64x64), mfma_f32_16x16x32_f16.
// LDS tiles XOR-swizzled on 16B granules with (row&7) to kill ds_read_b128
// bank conflicts (G4 / T2).
// ============================================================
__global__ __launch_bounds__(256, 2) void k3_qk(const u16* __restrict__ qB,
                                                const u16* __restrict__ kB,
                                                uint32_t* __restrict__ attnE){
    const int jt = blockIdx.x, it = blockIdx.y, b = blockIdx.z;
    const int t = threadIdx.x;
    const int w = t >> 6, l = t & 63;
    const int wi = w & 1, wj = w >> 1;
    const int l15 = l & 15, lq = l >> 4;
    __shared__ u16 lds[4 * 128 * 64];   // [tile=qk*2+m][row][c(64, swizzled granules)]

    f32x4 acc[2][4][4] = {};

    const int srow = t >> 1, shalf = t & 1;
    for (int bk = 0; bk < 4; ++bk){
        #pragma unroll
        for (int tile = 0; tile < 4; ++tile){     // 0,1 = q(m0,m1); 2,3 = k(m0,m1)
            const int qk = tile >> 1, m = tile & 1;
            const u16* sp = qk ? kB : qB;
            const int row0 = (qk ? jt : it) * 128;
            const u16* g = sp + (size_t)((b*M_ + m)*N_ + row0 + srow) * D_ + bk*64 + shalf*32;
            const uint4* gp = (const uint4*)g;
            uint4 v0 = gp[0], v1 = gp[1], v2 = gp[2], v3 = gp[3];
            u16* base = &lds[(tile*128 + srow) * 64];
            const int rs = srow & 7;
            *(uint4*)&base[((shalf*4 + 0) ^ rs) * 8] = v0;
            *(uint4*)&base[((shalf*4 + 1) ^ rs) * 8] = v1;
            *(uint4*)&base[((shalf*4 + 2) ^ rs) * 8] = v2;
            *(uint4*)&base[((shalf*4 + 3) ^ rs) * 8] = v3;
        }
        __syncthreads();
        #pragma unroll
        for (int ks = 0; ks < 2; ++ks){
            #pragma unroll
            for (int m = 0; m < 2; ++m){
                half8 a[4], bb[4];
                #pragma unroll
                for (int ti = 0; ti < 4; ++ti){
                    const int row = wi*64 + ti*16 + l15;
                    const int gr = (ks*4 + lq) ^ (row & 7);
                    a[ti] = *(const half8*)&lds[(m*128 + row)*64 + gr*8];
                }
                #pragma unroll
                for (int tj = 0; tj < 4; ++tj){
                    const int row = wj*64 + tj*16 + l15;
                    const int gr = (ks*4 + lq) ^ (row & 7);
                    bb[tj] = *(const half8*)&lds[((2 + m)*128 + row)*64 + gr*8];
                }
                #pragma unroll
                for (int ti = 0; ti < 4; ++ti)
                    #pragma unroll
                    for (int tj = 0; tj < 4; ++tj)
                        acc[m][ti][tj] = __builtin_amdgcn_mfma_f32_16x16x32_f16(
                            a[ti], bb[tj], acc[m][ti][tj], 0, 0, 0);
            }
        }
        __syncthreads();
    }

    const float INVT = 0.04419417382415922f;   // 1/sqrt(512)
    uint32_t* op = attnE + (size_t)b * N_ * N_;
    const int ibase = it*128 + wi*64;
    const int jbase = jt*128 + wj*64;
    #pragma unroll
    for (int ti = 0; ti < 4; ++ti){
        #pragma unroll
        for (int tj = 0; tj < 4; ++tj){
            #pragma unroll
            for (int rr = 0; rr < 4; ++rr){
                const int i = ibase + ti*16 + lq*4 + rr;   // C/D: row=(l>>4)*4+reg
                const int j = jbase + tj*16 + l15;         //      col=l&15
                const float e0 = __expf(acc[0][ti][tj][rr] * INVT);
                const float e1 = __expf(acc[1][ti][tj][rr] * INVT);
                op[(size_t)i * N_ + j] = pk16(e0, e1);
            }
        }
    }
}

// ============================================================
// K4: per 64-row block: (A) rowsums of E per mixture; (B) chunk loop over j:
// stage v chunk into LDS (f16), read E pairs -> write final attn fp32 in place
// + build PV A-fragments directly in registers, accumulate O with MFMA.
// ============================================================
__global__ __launch_bounds__(256, 2) void k4_pv(const float* __restrict__ vt,
                                                const u16* __restrict__ vB,  // may be null
                                                const float* __restrict__ wsLog,
                                                uint32_t* __restrict__ attnE,
                                                float* __restrict__ outO){
    const int itile = blockIdx.x, b = blockIdx.y;
    const int i0 = itile * 64;
    const int t = threadIdx.x, w = t >> 6, l = t & 63;
    const int l15 = l & 15, lq = l >> 4;
    __shared__ u16 v_lds[DV_ * 32];   // [dv][j-chunk 32], granule-swizzled with dv&3
    __shared__ float p0s[64], p1s[64];

    const float lg0 = wsLog[b*2 + 0], lg1 = wsLog[b*2 + 1];
    const float pi0 = 1.f / (1.f + __expf(lg1 - lg0));
    const float pi1 = 1.f / (1.f + __expf(lg0 - lg1));

    {   // ---- pass A: rowsums over packed f16 E
        const int rl = t >> 2, seg = t & 3;
        const uint4* e = (const uint4*)(attnE + (size_t)(b*N_ + i0 + rl)*N_ + seg*512);
        float s0 = 0.f, s1 = 0.f;
        for (int k = 0; k < 128; ++k){
            uint4 u = e[k];
            s0 += h2f_lo(u.x) + h2f_lo(u.y) + h2f_lo(u.z) + h2f_lo(u.w);
            s1 += h2f_hi(u.x) + h2f_hi(u.y) + h2f_hi(u.z) + h2f_hi(u.w);
        }
        s0 += __shfl_xor(s0, 1); s0 += __shfl_xor(s0, 2);
        s1 += __shfl_xor(s1, 1); s1 += __shfl_xor(s1, 2);
        if (seg == 0){ p0s[rl] = pi0 / s0; p1s[rl] = pi1 / s1; }
    }
    __syncthreads();

    f32x4 acc[32] = {};
    const int rl = w*16 + l15;
    const float p0 = p0s[rl], p1 = p1s[rl];
    uint32_t* erow = attnE + (size_t)(b*N_ + i0 + rl)*N_;

    for (int c = 0; c < 64; ++c){
        const int j0 = c * 32;
        {   // ---- stage v chunk [512 dv][32 j] as f16
            const int dv = t * 2;
            if (vB){
                const u16* g = vB + (size_t)(b*DV_ + dv)*N_ + j0;
                #pragma unroll
                for (int r = 0; r < 2; ++r){
                    const int dvr = dv + r;
                    const uint4* gp = (const uint4*)(g + (size_t)r * N_);
                    #pragma unroll
                    for (int q8 = 0; q8 < 4; ++q8)
                        *(uint4*)&v_lds[dvr*32 + ((q8 ^ (dvr & 3)) * 8)] = gp[q8];
                }
            } else {
                #pragma unroll
                for (int r = 0; r < 2; ++r){
                    const int dvr = dv + r;
                    const float* gr = vt + (size_t)(b*DV_ + dvr)*N_ + j0;
                    #pragma unroll
                    for (int q8 = 0; q8 < 4; ++q8){
                        float4 fA = *(const float4*)(gr + q8*8);
                        float4 fB = *(const float4*)(gr + q8*8 + 4);
                        uint4 u;
                        u.x = pk16(fA.x, fA.y);
                        u.y = pk16(fA.z, fA.w);
                        u.z = pk16(fB.x, fB.y);
                        u.w = pk16(fB.z, fB.w);
                        *(uint4*)&v_lds[dvr*32 + ((q8 ^ (dvr & 3)) * 8)] = u;
                    }
                }
            }
        }
        // ---- read E chunk (this wave's 16 rows), combine mixtures
        uint32_t* ep = erow + j0 + lq*8;
        uint4 u0 = *(const uint4*)ep;
        uint4 u1 = *(const uint4*)(ep + 4);
        float av[8];
        av[0] = p0*h2f_lo(u0.x) + p1*h2f_hi(u0.x);
        av[1] = p0*h2f_lo(u0.y) + p1*h2f_hi(u0.y);
        av[2] = p0*h2f_lo(u0.z) + p1*h2f_hi(u0.z);
        av[3] = p0*h2f_lo(u0.w) + p1*h2f_hi(u0.w);
        av[4] = p0*h2f_lo(u1.x) + p1*h2f_hi(u1.x);
        av[5] = p0*h2f_lo(u1.y) + p1*h2f_hi(u1.y);
        av[6] = p0*h2f_lo(u1.z) + p1*h2f_hi(u1.z);
        av[7] = p0*h2f_lo(u1.w) + p1*h2f_hi(u1.w);
        uint4 ua;
        ua.x = pk16(av[0], av[1]);
        ua.y = pk16(av[2], av[3]);
        ua.z = pk16(av[4], av[5]);
        ua.w = pk16(av[6], av[7]);
        union { uint4 u; half8 h; } cvt;
        cvt.u = ua;
        half8 af = cvt.h;

        __syncthreads();   // all E reads + v_lds writes complete

        // ---- overwrite the consumed E pairs with final attn fp32
        float4 w0 = make_float4(av[0], av[1], av[2], av[3]);
        float4 w1 = make_float4(av[4], av[5], av[6], av[7]);
        *(float4*)ep = w0;
        *(float4*)(ep + 4) = w1;

        // ---- PV: O[i, dv] += attn · v over this 32-j chunk
        #pragma unroll
        for (int n = 0; n < 32; ++n){
            const int dv = n*16 + l15;
            half8 bv = *(const half8*)&v_lds[dv*32 + ((lq ^ (dv & 3)) * 8)];
            acc[n] = __builtin_amdgcn_mfma_f32_16x16x32_f16(af, bv, acc[n], 0, 0, 0);
        }
        __syncthreads();   // protect v_lds for next chunk
    }

    #pragma unroll
    for (int n = 0; n < 32; ++n){
        #pragma unroll
        for (int rr = 0; rr < 4; ++rr){
            const int i = i0 + w*16 + lq*4 + rr;
            const int dv = n*16 + l15;
            outO[(size_t)(b*N_ + i)*DV_ + dv] = acc[n][rr];
        }
    }
}

// ============================================================
extern "C" void kernel_launch(void* const* d_in, const int* in_sizes, int n_in,
                              void* d_out, int out_size, void* d_ws, size_t ws_size,
                              hipStream_t stream){
    const float* qt  = (const float*)d_in[0];
    const float* kt  = (const float*)d_in[1];
    const float* vt  = (const float*)d_in[2];
    const float* wgt = (const float*)d_in[3];

    float* ws    = (float*)d_ws;
    float* wsLog = ws;          // 16 floats
    float* wsBar = ws + 16;     // 4096 floats

    u16* stage = (u16*)d_out;                       // qB at 0, kB after it
    u16* kB = stage + QB_U16;
    uint32_t* attnE = (uint32_t*)d_out + OUT_FLOATS; // attn region doubles as E scratch
    float* outO = (float*)d_out;

    const size_t vbBytes = (size_t)B_ * DV_ * N_ * 2;
    u16* vB = (ws_size >= (size_t)65536 + vbBytes)
                  ? (u16*)((char*)d_ws + 65536) : (u16*)nullptr;

    k0_transpose<<<dim3(32, 8, 16), 256, 0, stream>>>(qt, kt, stage);
    if (vB) k0_vconv<<<dim3(4096), 256, 0, stream>>>(vt, vB);
    k1_bar<<<dim3(64, 8), 256, 0, stream>>>(qt, wsBar);
    k2_logits<<<dim3(16), 64, 0, stream>>>(wgt, wsBar, wsLog);
    k3_qk<<<dim3(16, 16, 8), 256, 0, stream>>>(stage, kB, attnE);
    k4_pv<<<dim3(32, 8), 256, 0, stream>>>(vt, vB, wsLog, attnE, outO);
}

// Round 3
// 238.384 us; speedup vs baseline: 1.1335x; 1.1335x over previous
//
#include <hip/hip_runtime.h>
#include <stdint.h>

typedef unsigned short u16;
typedef float f32x4 __attribute__((ext_vector_type(4)));
typedef _Float16 half8 __attribute__((ext_vector_type(8)));
typedef __fp16 fp16x2 __attribute__((ext_vector_type(2)));

#define B_  8
#define M_  2
#define DK_ 512
#define D_  256
#define N_  2048
#define DV_ 512

#define OUT_FLOATS (B_*N_*DV_)     /* 8388608 */
#define QB_U16     (B_*M_*N_*D_)   /* 8388608 u16 elements = 16 MiB */

// ---- fp16 pack/unpack helpers -------------------------------------------
__device__ __forceinline__ uint32_t pk16(float a, float b){
    fp16x2 h = __builtin_amdgcn_cvt_pkrtz(a, b);      // v_cvt_pkrtz_f16_f32
    return __builtin_bit_cast(uint32_t, h);
}
__device__ __forceinline__ float h2f_lo(uint32_t u){
    return (float)__builtin_bit_cast(_Float16, (unsigned short)(u & 0xffffu));
}
__device__ __forceinline__ float h2f_hi(uint32_t u){
    return (float)__builtin_bit_cast(_Float16, (unsigned short)(u >> 16));
}

// ============================================================
// K0: transpose-convert qt,kt (fp32 [b, m*256+c, i]) -> f16 [ (b*2+m), row, c ]
// staged into the d_out "output" region (32 MiB, dead until K4 writes O).
// ============================================================
__global__ __launch_bounds__(256) void k0_transpose(const float* __restrict__ qt,
                                                    const float* __restrict__ kt,
                                                    u16* __restrict__ dstBase){
    const int it = blockIdx.x, yc = blockIdx.y, z = blockIdx.z;
    const int b = z & 7, src = z >> 3;
    const float* sp = src ? kt : qt;
    u16* dp = dstBase + (size_t)src * QB_U16;
    const int m = yc >> 2;
    const int cbase = (yc & 3) * 64;
    const int i0 = it * 64;
    __shared__ u16 lds[64 * 72];   // [i][c], pad 72 keeps 16B alignment (144B rows)
    const int t = threadIdx.x;
    {
        const int c_loc = t >> 2;
        const int iq = (t & 3) * 16;
        const float* g = sp + (size_t)(b*DK_ + m*D_ + cbase + c_loc) * N_ + i0 + iq;
        float vv[16];
        *(float4*)&vv[0]  = *(const float4*)(g + 0);
        *(float4*)&vv[4]  = *(const float4*)(g + 4);
        *(float4*)&vv[8]  = *(const float4*)(g + 8);
        *(float4*)&vv[12] = *(const float4*)(g + 12);
        #pragma unroll
        for (int e = 0; e < 16; ++e){
            _Float16 hf = (_Float16)vv[e];
            lds[(iq + e)*72 + c_loc] = __builtin_bit_cast(unsigned short, hf);
        }
    }
    __syncthreads();
    {
        const int i_loc = t >> 2;
        const int cq = (t & 3) * 16;
        uint4 a  = *(const uint4*)&lds[i_loc*72 + cq];
        uint4 b2 = *(const uint4*)&lds[i_loc*72 + cq + 8];
        u16* o = dp + (size_t)((b*M_ + m)*N_ + i0 + i_loc) * D_ + cbase + cq;
        *(uint4*)o = a;
        *(uint4*)(o + 8) = b2;
    }
}

// ============================================================
// K0v (optional, only if ws is big enough): vt fp32 -> f16, same layout.
// ============================================================
__global__ __launch_bounds__(256) void k0_vconv(const float* __restrict__ vt,
                                                u16* __restrict__ vB){
    size_t idx = ((size_t)blockIdx.x * 256 + threadIdx.x) * 8;
    const size_t total = (size_t)B_ * DV_ * N_;
    if (idx < total){
        float4 f0 = *(const float4*)(vt + idx);
        float4 f1 = *(const float4*)(vt + idx + 4);
        uint4 o;
        o.x = pk16(f0.x, f0.y);
        o.y = pk16(f0.z, f0.w);
        o.z = pk16(f1.x, f1.y);
        o.w = pk16(f1.z, f1.w);
        *(uint4*)(vB + idx) = o;
    }
}

// ============================================================
// K1: bar[b][c] = mean_i qt[b][c][i]
// ============================================================
__global__ __launch_bounds__(256) void k1_bar(const float* __restrict__ qt,
                                              float* __restrict__ bar){
    const int cg = blockIdx.x, b = blockIdx.y;
    const int t = threadIdx.x;
    const int c = cg*8 + (t >> 5);
    const int seg = t & 31;
    const float* g = qt + (size_t)(b*DK_ + c)*N_ + seg*64;
    float s = 0.f;
    #pragma unroll
    for (int k = 0; k < 16; ++k){
        float4 f = *(const float4*)(g + k*4);
        s += f.x + f.y + f.z + f.w;
    }
    s += __shfl_xor(s, 1); s += __shfl_xor(s, 2); s += __shfl_xor(s, 4);
    s += __shfl_xor(s, 8); s += __shfl_xor(s, 16);
    if (seg == 0) bar[b*DK_ + c] = s * (1.f / (float)N_);
}

// ============================================================
// K2: logits[b*2+m] = sum_c weight[m,c] * bar[b,c]
// ============================================================
__global__ void k2_logits(const float* __restrict__ wgt,
                          const float* __restrict__ bar,
                          float* __restrict__ wsLog){
    const int bm = blockIdx.x;
    const int b = bm >> 1, m = bm & 1;
    const int l = threadIdx.x; // 64
    float s = 0.f;
    #pragma unroll
    for (int k = 0; k < 8; ++k){
        const int c = l + k*64;
        s += wgt[m*DK_ + c] * bar[b*DK_ + c];
    }
    s += __shfl_xor(s, 1); s += __shfl_xor(s, 2); s += __shfl_xor(s, 4);
    s += __shfl_xor(s, 8); s += __shfl_xor(s, 16); s += __shfl_xor(s, 32);
    if (l == 0) wsLog[bm] = s;
}

// ============================================================
// K3: S = q·k for both mixtures, E = exp(S/sqrt(512)) packed as f16 pair
// (m0 lo, m1 hi) into the dword that will later hold attn[b,i,j] fp32.
// ============================================================
__global__ __launch_bounds__(256, 2) void k3_qk(const u16* __restrict__ qB,
                                                const u16* __restrict__ kB,
                                                uint32_t* __restrict__ attnE){
    const int jt = blockIdx.x, it = blockIdx.y, b = blockIdx.z;
    const int t = threadIdx.x;
    const int w = t >> 6, l = t & 63;
    const int wi = w & 1, wj = w >> 1;
    const int l15 = l & 15, lq = l >> 4;
    __shared__ u16 lds[4 * 128 * 64];   // [tile=qk*2+m][row][c(64, swizzled granules)]

    f32x4 acc[2][4][4] = {};

    const int srow = t >> 1, shalf = t & 1;
    for (int bk = 0; bk < 4; ++bk){
        #pragma unroll
        for (int tile = 0; tile < 4; ++tile){     // 0,1 = q(m0,m1); 2,3 = k(m0,m1)
            const int qk = tile >> 1, m = tile & 1;
            const u16* sp = qk ? kB : qB;
            const int row0 = (qk ? jt : it) * 128;
            const u16* g = sp + (size_t)((b*M_ + m)*N_ + row0 + srow) * D_ + bk*64 + shalf*32;
            const uint4* gp = (const uint4*)g;
            uint4 v0 = gp[0], v1 = gp[1], v2 = gp[2], v3 = gp[3];
            u16* base = &lds[(tile*128 + srow) * 64];
            const int rs = srow & 7;
            *(uint4*)&base[((shalf*4 + 0) ^ rs) * 8] = v0;
            *(uint4*)&base[((shalf*4 + 1) ^ rs) * 8] = v1;
            *(uint4*)&base[((shalf*4 + 2) ^ rs) * 8] = v2;
            *(uint4*)&base[((shalf*4 + 3) ^ rs) * 8] = v3;
        }
        __syncthreads();
        #pragma unroll
        for (int ks = 0; ks < 2; ++ks){
            #pragma unroll
            for (int m = 0; m < 2; ++m){
                half8 a[4], bb[4];
                #pragma unroll
                for (int ti = 0; ti < 4; ++ti){
                    const int row = wi*64 + ti*16 + l15;
                    const int gr = (ks*4 + lq) ^ (row & 7);
                    a[ti] = *(const half8*)&lds[(m*128 + row)*64 + gr*8];
                }
                #pragma unroll
                for (int tj = 0; tj < 4; ++tj){
                    const int row = wj*64 + tj*16 + l15;
                    const int gr = (ks*4 + lq) ^ (row & 7);
                    bb[tj] = *(const half8*)&lds[((2 + m)*128 + row)*64 + gr*8];
                }
                #pragma unroll
                for (int ti = 0; ti < 4; ++ti)
                    #pragma unroll
                    for (int tj = 0; tj < 4; ++tj)
                        acc[m][ti][tj] = __builtin_amdgcn_mfma_f32_16x16x32_f16(
                            a[ti], bb[tj], acc[m][ti][tj], 0, 0, 0);
            }
        }
        __syncthreads();
    }

    const float INVT = 0.04419417382415922f;   // 1/sqrt(512)
    uint32_t* op = attnE + (size_t)b * N_ * N_;
    const int ibase = it*128 + wi*64;
    const int jbase = jt*128 + wj*64;
    #pragma unroll
    for (int ti = 0; ti < 4; ++ti){
        #pragma unroll
        for (int tj = 0; tj < 4; ++tj){
            #pragma unroll
            for (int rr = 0; rr < 4; ++rr){
                const int i = ibase + ti*16 + lq*4 + rr;   // C/D: row=(l>>4)*4+reg
                const int j = jbase + tj*16 + l15;         //      col=l&15
                const float e0 = __expf(acc[0][ti][tj][rr] * INVT);
                const float e1 = __expf(acc[1][ti][tj][rr] * INVT);
                op[(size_t)i * N_ + j] = pk16(e0, e1);
            }
        }
    }
}

// ============================================================
// K3.5: coalesced per-row sums of packed E, -> wsScale[b][i] = {pi0/s0, pi1/s1}.
// One wave per row: 64 lanes x uint4 = 1KB contiguous per instruction.
// ============================================================
__global__ __launch_bounds__(256) void k35_rowsum(const uint32_t* __restrict__ attnE,
                                                  const float* __restrict__ wsLog,
                                                  float* __restrict__ wsScale){
    const int blk = blockIdx.x;              // 4096 blocks, 4 rows each
    const int b = blk >> 9;
    const int w = threadIdx.x >> 6, l = threadIdx.x & 63;
    const int i = (blk & 511)*4 + w;
    const uint4* e = (const uint4*)(attnE + ((size_t)b*N_ + i)*N_);
    float s0 = 0.f, s1 = 0.f;
    #pragma unroll
    for (int k = 0; k < 8; ++k){
        uint4 u = e[k*64 + l];
        s0 += h2f_lo(u.x) + h2f_lo(u.y) + h2f_lo(u.z) + h2f_lo(u.w);
        s1 += h2f_hi(u.x) + h2f_hi(u.y) + h2f_hi(u.z) + h2f_hi(u.w);
    }
    s0 += __shfl_xor(s0, 1);  s1 += __shfl_xor(s1, 1);
    s0 += __shfl_xor(s0, 2);  s1 += __shfl_xor(s1, 2);
    s0 += __shfl_xor(s0, 4);  s1 += __shfl_xor(s1, 4);
    s0 += __shfl_xor(s0, 8);  s1 += __shfl_xor(s1, 8);
    s0 += __shfl_xor(s0, 16); s1 += __shfl_xor(s1, 16);
    s0 += __shfl_xor(s0, 32); s1 += __shfl_xor(s1, 32);
    if (l == 0){
        const float lg0 = wsLog[b*2 + 0], lg1 = wsLog[b*2 + 1];
        const float pi0 = 1.f / (1.f + __expf(lg1 - lg0));
        const float pi1 = 1.f / (1.f + __expf(lg0 - lg1));
        wsScale[((size_t)b*N_ + i)*2 + 0] = pi0 / s0;
        wsScale[((size_t)b*N_ + i)*2 + 1] = pi1 / s1;
    }
}

// ============================================================
// K4 v2: 512 threads = 8 waves (4 row-groups x 2 dv-halves), 64 rows/block.
// Double-buffered v chunk [512 dv][32 j] f16 in LDS, single barrier/chunk,
// v loads + E loads prefetched one chunk ahead (drained by the barrier AFTER
// the MFMAs -> latency hidden under compute). Read swizzle lq^(l15>>2)
// gives balanced 2-way LDS access (free).
// ============================================================
template<bool HASVB>
__global__ __launch_bounds__(512) void k4_pv(const float* __restrict__ vt,
                                             const u16* __restrict__ vB,
                                             const float* __restrict__ wsScale,
                                             uint32_t* __restrict__ attnE,
                                             float* __restrict__ outO){
    const int itile = blockIdx.x, b = blockIdx.y;
    const int i0 = itile * 64;
    const int t = threadIdx.x;
    const int l = t & 63, w = t >> 6;
    const int l15 = l & 15, lq = l >> 4;
    const int rowgrp = w & 3, dvh = w >> 2;
    __shared__ u16 v_lds[2][512 * 32];   // 64 KiB total

    const int rl = rowgrp*16 + l15;                    // A-frag row (0..63)
    const float2 p01 = *(const float2*)&wsScale[((size_t)(b*N_ + i0 + rl))*2];
    const float p0 = p01.x, p1 = p01.y;
    uint32_t* erow = attnE + (size_t)(b*N_ + i0 + rl) * N_;

    const int vswz  = (t >> 2) & 3;                    // write-side granule XOR
    const int rslot = lq ^ (l15 >> 2);                 // read-side slot

    const u16*   gv16 = vB + (size_t)(b*DV_ + t)*N_;
    const float* gv32 = vt + (size_t)(b*DV_ + t)*N_;

    uint4  rv[4];
    float4 rf[8];

    auto issue_load = [&](int c){
        const int j0 = c*32;
        if (HASVB){
            const uint4* gp = (const uint4*)(gv16 + j0);
            rv[0] = gp[0]; rv[1] = gp[1]; rv[2] = gp[2]; rv[3] = gp[3];
        } else {
            const float4* gp = (const float4*)(gv32 + j0);
            #pragma unroll
            for (int q = 0; q < 8; ++q) rf[q] = gp[q];
        }
    };
    auto write_lds = [&](int buf){
        u16* base = &v_lds[buf][t*32];
        #pragma unroll
        for (int G = 0; G < 4; ++G){
            uint4 u;
            if (HASVB){
                u = rv[G];
            } else {
                u.x = pk16(rf[2*G].x,   rf[2*G].y);
                u.y = pk16(rf[2*G].z,   rf[2*G].w);
                u.z = pk16(rf[2*G+1].x, rf[2*G+1].y);
                u.w = pk16(rf[2*G+1].z, rf[2*G+1].w);
            }
            *(uint4*)&base[(G ^ vswz)*8] = u;
        }
    };

    f32x4 acc[16] = {};

    issue_load(0);
    write_lds(0);
    issue_load(1);
    uint4 e0 = *(const uint4*)(erow + lq*8);
    uint4 e1 = *(const uint4*)(erow + lq*8 + 4);
    __syncthreads();

    int cur = 0;
    for (int c = 0; c < 64; ++c){
        if (c + 1 < 64) write_lds(cur ^ 1);            // chunk c+1 (loaded last iter)
        if (c + 2 < 64) issue_load(c + 2);             // in flight across barrier
        uint4 en0, en1;
        if (c + 1 < 64){                               // E prefetch for next chunk
            en0 = *(const uint4*)(erow + (c+1)*32 + lq*8);
            en1 = *(const uint4*)(erow + (c+1)*32 + lq*8 + 4);
        }
        float av[8];
        av[0] = p0*h2f_lo(e0.x) + p1*h2f_hi(e0.x);
        av[1] = p0*h2f_lo(e0.y) + p1*h2f_hi(e0.y);
        av[2] = p0*h2f_lo(e0.z) + p1*h2f_hi(e0.z);
        av[3] = p0*h2f_lo(e0.w) + p1*h2f_hi(e0.w);
        av[4] = p0*h2f_lo(e1.x) + p1*h2f_hi(e1.x);
        av[5] = p0*h2f_lo(e1.y) + p1*h2f_hi(e1.y);
        av[6] = p0*h2f_lo(e1.z) + p1*h2f_hi(e1.z);
        av[7] = p0*h2f_lo(e1.w) + p1*h2f_hi(e1.w);
        if (dvh == 0){                                 // finalize attn in place
            float* ap = (float*)(erow + c*32 + lq*8);
            *(float4*)ap       = make_float4(av[0], av[1], av[2], av[3]);
            *(float4*)(ap + 4) = make_float4(av[4], av[5], av[6], av[7]);
        }
        uint4 ua;
        ua.x = pk16(av[0], av[1]);
        ua.y = pk16(av[2], av[3]);
        ua.z = pk16(av[4], av[5]);
        ua.w = pk16(av[6], av[7]);
        union { uint4 u; half8 h; } cvt;
        cvt.u = ua;
        half8 af = cvt.h;

        const u16* vb = &v_lds[cur][(dvh*256 + l15)*32 + rslot*8];
        #pragma unroll
        for (int n = 0; n < 16; ++n){
            half8 bv = *(const half8*)(vb + n*512);    // row stride 16*32 u16
            acc[n] = __builtin_amdgcn_mfma_f32_16x16x32_f16(af, bv, acc[n], 0, 0, 0);
        }
        if (c + 1 < 64){ e0 = en0; e1 = en1; }
        __syncthreads();
        cur ^= 1;
    }

    #pragma unroll
    for (int n = 0; n < 16; ++n){
        #pragma unroll
        for (int rr = 0; rr < 4; ++rr){
            const int i  = i0 + rowgrp*16 + lq*4 + rr;  // C/D: row=(l>>4)*4+reg
            const int dv = dvh*256 + n*16 + l15;        //      col=l&15
            outO[(size_t)(b*N_ + i)*DV_ + dv] = acc[n][rr];
        }
    }
}

// ============================================================
extern "C" void kernel_launch(void* const* d_in, const int* in_sizes, int n_in,
                              void* d_out, int out_size, void* d_ws, size_t ws_size,
                              hipStream_t stream){
    const float* qt  = (const float*)d_in[0];
    const float* kt  = (const float*)d_in[1];
    const float* vt  = (const float*)d_in[2];
    const float* wgt = (const float*)d_in[3];

    float* ws      = (float*)d_ws;
    float* wsLog   = ws;          // 16 floats
    float* wsBar   = ws + 16;     // 4096 floats
    float* wsScale = (float*)((char*)d_ws + 32768);   // 32768 floats = 128 KiB

    u16* stage = (u16*)d_out;                        // qB at 0, kB after it
    u16* kB = stage + QB_U16;
    uint32_t* attnE = (uint32_t*)d_out + OUT_FLOATS; // attn region doubles as E scratch
    float* outO = (float*)d_out;

    const size_t vbBytes = (size_t)B_ * DV_ * N_ * 2;
    u16* vB = (ws_size >= (size_t)262144 + vbBytes)
                  ? (u16*)((char*)d_ws + 262144) : (u16*)nullptr;

    k0_transpose<<<dim3(32, 8, 16), 256, 0, stream>>>(qt, kt, stage);
    if (vB) k0_vconv<<<dim3(4096), 256, 0, stream>>>(vt, vB);
    k1_bar<<<dim3(64, 8), 256, 0, stream>>>(qt, wsBar);
    k2_logits<<<dim3(16), 64, 0, stream>>>(wgt, wsBar, wsLog);
    k3_qk<<<dim3(16, 16, 8), 256, 0, stream>>>(stage, kB, attnE);
    k35_rowsum<<<dim3(4096), 256, 0, stream>>>(attnE, wsLog, wsScale);
    if (vB) k4_pv<true ><<<dim3(32, 8), 512, 0, stream>>>(vt, vB, wsScale, attnE, outO);
    else    k4_pv<false><<<dim3(32, 8), 512, 0, stream>>>(vt, vB, wsScale, attnE, outO);
}